// Round 9
// baseline (207.344 us; speedup 1.0000x reference)
//
#include <hip/hip_runtime.h>

#define EPS 1e-5f
#define B 16
#define CH 22
#define T_IN 1001
#define F 36
#define RF 65
#define T1 937            // T_IN - RF + 1
#define FC 792            // F*CH
#define TW 64             // front t-tile
#define NTW 15            // ceil(937/64)
#define CSPL 3            // front ch-split
#define QSPL 12           // qconv f-split (3 f each)
#define UN 885            // valid u range for Q/E
#define PSPAN 304         // qconv staged span per f row
#define KS 15
#define GN 295
#define WN 129
#define M43 43
#define BF 576            // B*F
#define FLAT 1548         // F*43

// workspace float offsets
#define H2P_OFF 0                 // 3*576*937     = 1,619,136
#define EP_OFF  1619136           // + 12*576*885  = 6,117,120
#define WTP_OFF 7736256           // + 4*65*9      =     2,340
#define WSP_OFF 7738596           // + 4*22*36*9   =    28,512
#define WCT_OFF 7767108           // + 36*15*36    =    19,440
#define BN_OFF  7786548           // + 6*36

__device__ __forceinline__ float elu_f(float v) {
    return v > 0.f ? v : (__expf(v) - 1.f);
}

// ---- prep: pack weights per-9-fi-group + bn scale/offset + init out --------
__global__ __launch_bounds__(256) void k_prep(
    const float* __restrict__ w_t, const float* __restrict__ w_s,
    const float* __restrict__ w_c,
    const float* __restrict__ b_t, const float* __restrict__ g_t,
    const float* __restrict__ be_t,const float* __restrict__ m_t,
    const float* __restrict__ v_t,
    const float* __restrict__ b_s, const float* __restrict__ g_s,
    const float* __restrict__ be_s,const float* __restrict__ m_s,
    const float* __restrict__ v_s,
    const float* __restrict__ b_c, const float* __restrict__ g_c,
    const float* __restrict__ be_c,const float* __restrict__ m_c,
    const float* __restrict__ v_c, const float* __restrict__ b_fc,
    float* __restrict__ wtP, float* __restrict__ wsP,
    float* __restrict__ wcT, float* __restrict__ bnz,
    float* __restrict__ out)
{
    int i = blockIdx.x * 256 + threadIdx.x;
    if (i < 4 * RF * 9) {               // wtP[g][k][jj] = w_t[9g+jj][k]
        int jj = i % 9, k = (i / 9) % RF, g = i / (9 * RF);
        wtP[i] = w_t[(9 * g + jj) * RF + k];
    }
    if (i < 4 * CH * F * 9) {           // wsP[g][ch][fo][jj] = w_s[fo][9g+jj][ch]
        int jj = i % 9, fo = (i / 9) % F, ch = (i / (9 * F)) % CH, g = i / (9 * F * CH);
        wsP[i] = w_s[(fo * F + 9 * g + jj) * CH + ch];
    }
    if (i < F * KS * F) {               // wcT[f][k][fo]
        int fk = i / F, fo = i % F; int f = fk / KS, k = fk % KS;
        wcT[i] = w_c[(fo * F + f) * KS + k];
    }
    if (i < F) {
        float s1 = g_t[i] * rsqrtf(v_t[i] + EPS);
        bnz[i]          = s1;
        bnz[F + i]      = (b_t[i] - m_t[i]) * s1 + be_t[i];
        float s2 = g_s[i] * rsqrtf(v_s[i] + EPS);
        bnz[2 * F + i]  = s2;
        bnz[3 * F + i]  = (b_s[i] - m_s[i]) * s2 + be_s[i];
        float s3 = g_c[i] * rsqrtf(v_c[i] + EPS);
        bnz[4 * F + i]  = s3;
        bnz[5 * F + i]  = (b_c[i] - m_c[i]) * s3 + be_c[i];
    }
    if (i < B * 4) out[i] = b_fc[i & 3];
}

// ---- K1: fused temporal+spatial conv, ch-split partials -> h2p[3] ----------
// grid (NTW, CSPL, B); 256 thr = 4 waves; wave g owns fi {9g..9g+8}; lane = t.
// h1 lives only in registers; per-ch consume into acc[36]; 2-row LDS reduce.
__global__ __launch_bounds__(256) void k_front(
    const float* __restrict__ x, const float* __restrict__ wtP,
    const float* __restrict__ wsP, const float* __restrict__ bnz,
    float* __restrict__ h2p)
{
    __shared__ float Ls[2 * F * TW];   // 18.4 KB
    const int tid = threadIdx.x;
    const int lane = tid & 63;
    const int g = __builtin_amdgcn_readfirstlane(tid >> 6);   // 0..3
    const int chg = blockIdx.y, b = blockIdx.z;
    const int ch0 = (chg == 0) ? 0 : (8 + (chg - 1) * 7);
    const int nch = (chg == 0) ? 8 : 7;
    const int t0 = blockIdx.x * TW;
    int t = t0 + lane;
    int tc = t < T1 ? t : (T1 - 1);

    float s1v[9], o1v[9];
    #pragma unroll
    for (int jj = 0; jj < 9; ++jj) {
        s1v[jj] = bnz[9 * g + jj];
        o1v[jj] = bnz[F + 9 * g + jj];
    }

    float acc[F];
    #pragma unroll
    for (int j = 0; j < F; ++j) acc[j] = 0.f;

    for (int c = 0; c < nch; ++c) {
        const int ch = ch0 + c;
        const float* xp = x + (b * CH + ch) * T_IN + tc;
        float h[9];
        #pragma unroll
        for (int jj = 0; jj < 9; ++jj) h[jj] = 0.f;

        #pragma unroll 5
        for (int k = 0; k < RF; ++k) {
            float xv = xp[k];                        // 1 load per 9 FMA
            const float* wr = wtP + (g * RF + k) * 9; // contiguous -> wide s_load
            #pragma unroll
            for (int jj = 0; jj < 9; ++jj) h[jj] += xv * wr[jj];
        }

        float e[9];
        #pragma unroll
        for (int jj = 0; jj < 9; ++jj)
            e[jj] = elu_f(h[jj] * s1v[jj] + o1v[jj]);

        const float* wq = wsP + ((size_t)(g * CH + ch) * F) * 9;
        #pragma unroll
        for (int fo = 0; fo < F; ++fo) {
            const float* wrr = wq + fo * 9;          // contiguous 9 scalars
            float a = acc[fo];
            #pragma unroll
            for (int jj = 0; jj < 9; ++jj) a += e[jj] * wrr[jj];
            acc[fo] = a;
        }
    }

    // reduce 4 waves through 2 LDS rows
    float* row = &Ls[(size_t)(g & 1) * (F * TW)];
    if (g < 2) {
        #pragma unroll
        for (int fo = 0; fo < F; ++fo) row[fo * TW + lane] = acc[fo];
    }
    __syncthreads();
    if (g >= 2) {
        #pragma unroll
        for (int fo = 0; fo < F; ++fo) row[fo * TW + lane] += acc[fo];
    }
    __syncthreads();

    for (int i = tid; i < F * TW; i += 256) {
        float s = Ls[i] + Ls[F * TW + i];
        int fo = i / TW, tl = i % TW;
        int tg = t0 + tl;
        if (tg < T1)
            h2p[(((size_t)chg * B + b) * F + fo) * T1 + tg] = s;
    }
}

// ---- K2: combine h2p + bn_s + elu + pool3, dilated conv -> Ep[12] ----------
// grid (4, QSPL, B); 4 waves = 4 u-subchunks; wave = 64 u x 36 fo; nf = 3
__global__ __launch_bounds__(256) void k_qconv(
    const float* __restrict__ h2p, const float* __restrict__ wcT,
    const float* __restrict__ bnz, float* __restrict__ Ep)
{
    __shared__ float Ps[3 * PSPAN];   // 3.6 KB
    const int tid = threadIdx.x;
    const int slice = blockIdx.y, b = blockIdx.z;
    const int u0 = blockIdx.x * 256;
    const int f_base = slice * 3;

    for (int i = tid; i < 3 * PSPAN; i += 256) {
        int fl = i / PSPAN, j = i % PSPAN;
        int f = f_base + fl;
        float s2 = bnz[2 * F + f], o2 = bnz[3 * F + f];
        const float* p0 = h2p + ((size_t)(0 * B + b) * F + f) * T1;
        const float* p1 = h2p + ((size_t)(1 * B + b) * F + f) * T1;
        const float* p2 = h2p + ((size_t)(2 * B + b) * F + f) * T1;
        float a = 0.f;
        #pragma unroll
        for (int d = 0; d < 3; ++d) {
            int s = u0 + j + d; if (s > T1 - 1) s = T1 - 1;
            float q = p0[s] + p1[s] + p2[s];
            a += elu_f(q * s2 + o2);
        }
        Ps[i] = a * (1.f / 3.f);
    }
    __syncthreads();

    const int lu = tid;                        // wave = 64 consecutive u

    float acc[F];
    #pragma unroll
    for (int j = 0; j < F; ++j) acc[j] = 0.f;

    #pragma unroll
    for (int fl = 0; fl < 3; ++fl) {
        const int pb = fl * PSPAN + lu;
        #pragma unroll 5
        for (int k = 0; k < KS; ++k) {
            float pv = Ps[pb + 3 * k];
            const float* wr = wcT + ((f_base + fl) * KS + k) * F;  // uniform
            #pragma unroll
            for (int j = 0; j < F; ++j) acc[j] += pv * wr[j];
        }
    }

    int u_g = u0 + lu;
    if (u_g < UN) {
        #pragma unroll
        for (int j = 0; j < F; ++j)
            Ep[(((size_t)slice * B + b) * F + j) * UN + u_g] = acc[j];
    }
}

// ---- K3: combine Ep[12] + bn_c + elu, window sums, fused FC -> out ---------
__global__ __launch_bounds__(256) void k_wins(
    const float* __restrict__ Ep, const float* __restrict__ bnz,
    const float* __restrict__ w_fc, float* __restrict__ out)
{
    __shared__ float Es[UN];
    __shared__ float G[GN];
    __shared__ float Ws[WN];
    __shared__ float Sm[M43];
    const int tid = threadIdx.x;
    const int bf = blockIdx.x;
    const int b = bf / F, f = bf % F;
    const float sc = bnz[4 * F + f];
    const float oc = bnz[5 * F + f];
    for (int i = tid; i < UN; i += 256) {
        float s = 0.f;
        #pragma unroll
        for (int sl = 0; sl < QSPL; ++sl)
            s += Ep[((size_t)sl * BF + bf) * UN + i];
        Es[i] = elu_f(s * sc + oc);
    }
    __syncthreads();
    for (int q = tid; q < GN; q += 256)
        G[q] = Es[3 * q] + Es[3 * q + 1] + Es[3 * q + 2];
    __syncthreads();
    if (tid < WN) {
        float a = 0.f;
        for (int q = tid; q < tid + 167; ++q) a += G[q];
        Ws[tid] = a;
    }
    __syncthreads();
    if (tid < M43)
        Sm[tid] = (Ws[3 * tid] + Ws[3 * tid + 1] + Ws[3 * tid + 2]) * (1.f / 3.f);
    __syncthreads();
    if (tid < 4) {
        const float* wr = w_fc + tid * FLAT + f * M43;
        float a = 0.f;
        #pragma unroll 43
        for (int m = 0; m < M43; ++m) a += Sm[m] * wr[m];
        atomicAdd(&out[b * 4 + tid], a * (1.f / 501.f));
    }
}

extern "C" void kernel_launch(void* const* d_in, const int* in_sizes, int n_in,
                              void* d_out, int out_size, void* d_ws, size_t ws_size,
                              hipStream_t stream) {
    const float* x    = (const float*)d_in[0];
    const float* w_t  = (const float*)d_in[1];
    const float* b_t  = (const float*)d_in[2];
    const float* g_t  = (const float*)d_in[3];
    const float* be_t = (const float*)d_in[4];
    const float* m_t  = (const float*)d_in[5];
    const float* v_t  = (const float*)d_in[6];
    const float* w_s  = (const float*)d_in[7];
    const float* b_s  = (const float*)d_in[8];
    const float* g_s  = (const float*)d_in[9];
    const float* be_s = (const float*)d_in[10];
    const float* m_s  = (const float*)d_in[11];
    const float* v_s  = (const float*)d_in[12];
    const float* w_c  = (const float*)d_in[13];
    const float* b_c  = (const float*)d_in[14];
    const float* g_c  = (const float*)d_in[15];
    const float* be_c = (const float*)d_in[16];
    const float* m_c  = (const float*)d_in[17];
    const float* v_c  = (const float*)d_in[18];
    const float* w_fc = (const float*)d_in[19];
    const float* b_fc = (const float*)d_in[20];

    float* ws  = (float*)d_ws;
    float* h2p = ws + H2P_OFF;
    float* Ep  = ws + EP_OFF;
    float* wtP = ws + WTP_OFF;
    float* wsP = ws + WSP_OFF;
    float* wcT = ws + WCT_OFF;
    float* bnz = ws + BN_OFF;
    float* out = (float*)d_out;

    k_prep<<<dim3(112), 256, 0, stream>>>(
        w_t, w_s, w_c, b_t, g_t, be_t, m_t, v_t,
        b_s, g_s, be_s, m_s, v_s, b_c, g_c, be_c, m_c, v_c, b_fc,
        wtP, wsP, wcT, bnz, out);

    k_front<<<dim3(NTW, CSPL, B), 256, 0, stream>>>(x, wtP, wsP, bnz, h2p);
    k_qconv<<<dim3(4, QSPL, B), 256, 0, stream>>>(h2p, wcT, bnz, Ep);
    k_wins<<<dim3(BF), 256, 0, stream>>>(Ep, bnz, w_fc, out);
}

// Round 10
// 176.424 us; speedup vs baseline: 1.1753x; 1.1753x over previous
//
#include <hip/hip_runtime.h>

#define EPS 1e-5f
#define B 16
#define CH 22
#define T_IN 1001
#define F 36
#define RF 65
#define T1 937            // T_IN - RF + 1
#define FC 792            // F*CH
#define KW 99             // sconv per-wave K slice (FC/8)
#define UN 885            // valid u range for Q/E
#define PSPAN 304         // qconv staged span per f row
#define KS 15
#define GN 295
#define WN 129
#define M43 43
#define BF 576            // B*F
#define FLAT 1548         // F*43

// workspace float offsets
#define H2_OFF  0                 // 576*937       =   539,712
#define EP_OFF  539712            // + 8*576*885   = 4,078,080
#define WTT_OFF 4617792           // + 36*65       =     2,340
#define WST_OFF 4620132           // + 792*36      =    28,512
#define WCT_OFF 4648644           // + 36*15*36    =    19,440
#define BN_OFF  4668084           // + 6*36       =       216
#define H1_OFF  4668352           // h1 (slabbed if scratch is tight)

__device__ __forceinline__ float elu_f(float v) {
    return v > 0.f ? v : (__expf(v) - 1.f);
}

// ---- prep: transpose weights + bn scale/offset + init out with bias --------
__global__ __launch_bounds__(256) void k_prep(
    const float* __restrict__ w_t, const float* __restrict__ w_s,
    const float* __restrict__ w_c,
    const float* __restrict__ b_t, const float* __restrict__ g_t,
    const float* __restrict__ be_t,const float* __restrict__ m_t,
    const float* __restrict__ v_t,
    const float* __restrict__ b_s, const float* __restrict__ g_s,
    const float* __restrict__ be_s,const float* __restrict__ m_s,
    const float* __restrict__ v_s,
    const float* __restrict__ b_c, const float* __restrict__ g_c,
    const float* __restrict__ be_c,const float* __restrict__ m_c,
    const float* __restrict__ v_c, const float* __restrict__ b_fc,
    float* __restrict__ wtT, float* __restrict__ wsT,
    float* __restrict__ wcT, float* __restrict__ bnz,
    float* __restrict__ out)
{
    int i = blockIdx.x * 256 + threadIdx.x;
    if (i < F * RF)     { int k = i / F,  fi = i % F; wtT[i] = w_t[fi * RF + k]; }
    if (i < FC * F)     { int fc = i / F, fo = i % F; wsT[i] = w_s[fo * FC + fc]; }
    if (i < F * KS * F) { int fk = i / F, fo = i % F; int f = fk / KS, k = fk % KS;
                          wcT[i] = w_c[(fo * F + f) * KS + k]; }
    if (i < F) {
        float s1 = g_t[i] * rsqrtf(v_t[i] + EPS);
        bnz[i]          = s1;
        bnz[F + i]      = (b_t[i] - m_t[i]) * s1 + be_t[i];
        float s2 = g_s[i] * rsqrtf(v_s[i] + EPS);
        bnz[2 * F + i]  = s2;
        bnz[3 * F + i]  = (b_s[i] - m_s[i]) * s2 + be_s[i];
        float s3 = g_c[i] * rsqrtf(v_c[i] + EPS);
        bnz[4 * F + i]  = s3;
        bnz[5 * F + i]  = (b_c[i] - m_c[i]) * s3 + be_c[i];
    }
    if (i < B * 4) out[i] = b_fc[i & 3];
}

// ---- K1a: temporal conv + bn + elu -> h1[b][fi][ch][t] (slab) --------------
// grid (ceil(TSeff/256), CH, B); 4 waves; wave = 64 consecutive t x 36 fi.
// x loads vectorized float4 along k (contiguous): 374 loads / 2340 FMA.
__global__ __launch_bounds__(256) void k_tconv(
    const float* __restrict__ x, const float* __restrict__ wtT,
    const float* __restrict__ bnz, float* __restrict__ h1,
    int t_base, int TS, int TSeff)
{
    const int tloc = blockIdx.x * 256 + threadIdx.x;
    const int b = blockIdx.z, ch = blockIdx.y;
    int t = t_base + tloc;
    int tc = t < (T1 - 1) ? t : (T1 - 1);
    const float* xp = x + (b * CH + ch) * T_IN + tc;

    float acc[F];
    #pragma unroll
    for (int j = 0; j < F; ++j) acc[j] = 0.f;

    // 16 float4 loads cover k = 0..63 (dwordx4 is dword-aligned-safe on CDNA)
    #pragma unroll 4
    for (int kk = 0; kk < 16; ++kk) {
        float4 xv4 = *(const float4*)(xp + 4 * kk);
        const float* wr0 = wtT + (4 * kk + 0) * F;   // 144 consecutive floats
        const float* wr1 = wtT + (4 * kk + 1) * F;   // -> wide s_loads
        const float* wr2 = wtT + (4 * kk + 2) * F;
        const float* wr3 = wtT + (4 * kk + 3) * F;
        #pragma unroll
        for (int j = 0; j < F; ++j) {
            acc[j] += xv4.x * wr0[j];
            acc[j] += xv4.y * wr1[j];
            acc[j] += xv4.z * wr2[j];
            acc[j] += xv4.w * wr3[j];
        }
    }
    {   // tail k = 64
        float xv = xp[64];
        const float* wr = wtT + 64 * F;
        #pragma unroll
        for (int j = 0; j < F; ++j) acc[j] += xv * wr[j];
    }

    if (t < T1 && tloc < TSeff) {
        #pragma unroll
        for (int j = 0; j < F; ++j) {
            float s1 = bnz[j], o1 = bnz[F + j];
            h1[((size_t)(b * F + j) * CH + ch) * TS + tloc] =
                elu_f(acc[j] * s1 + o1);
        }
    }
}

// ---- K1b: 1x1 spatial conv, in-block 8-way split-K + bn + elu -> h2 --------
// grid (ceil(TSeff/64), B); 512 thr = 8 waves = 8 K-slices of same 64 t
__global__ __launch_bounds__(512) void k_sconv(
    const float* __restrict__ h1, const float* __restrict__ wsT,
    const float* __restrict__ bnz, float* __restrict__ h2,
    int t_base, int TS, int TSeff)
{
    __shared__ float Ls[8 * F * 64];   // 73.7 KB
    const int tid = threadIdx.x;
    const int lane = tid & 63;
    const int w = __builtin_amdgcn_readfirstlane(tid >> 6);   // K-slice 0..7
    const int b = blockIdx.y;
    const int tl0 = blockIdx.x * 64;
    int tl = tl0 + lane;
    int tlc = tl < (TSeff - 1) ? tl : (TSeff - 1);

    const float* hq = h1 + ((size_t)b * FC + w * KW) * TS + tlc;
    const float* wb = wsT + (w * KW) * F;

    float acc[F];
    #pragma unroll
    for (int j = 0; j < F; ++j) acc[j] = 0.f;

    #pragma unroll 11
    for (int fc = 0; fc < KW; ++fc) {
        float hv = hq[(size_t)fc * TS];        // 256B coalesced, L2/L3
        const float* wr = wb + fc * F;         // wave-uniform -> wide s_load
        #pragma unroll
        for (int j = 0; j < F; ++j) acc[j] += hv * wr[j];
    }

    #pragma unroll
    for (int j = 0; j < F; ++j) Ls[(w * F + j) * 64 + lane] = acc[j];
    __syncthreads();

    for (int i = tid; i < F * 64; i += 512) {
        float s = 0.f;
        #pragma unroll
        for (int wq = 0; wq < 8; ++wq) s += Ls[wq * (F * 64) + i];
        int fo = i >> 6;
        int tloc2 = tl0 + (i & 63);
        int tg = t_base + tloc2;
        if (tloc2 < TSeff) {
            float s2 = bnz[2 * F + fo], o2 = bnz[3 * F + fo];
            h2[(b * F + fo) * T1 + tg] = elu_f(s * s2 + o2);
        }
    }
}

// ---- K2: fused pool3 + dilated conv over h2 -> raw partials Ep -------------
// grid (4, 8, B); 4 waves = 4 u-subchunks; wave = 64 u x 36 fo
__global__ __launch_bounds__(256) void k_qconv(
    const float* __restrict__ h2, const float* __restrict__ wcT,
    float* __restrict__ Ep)
{
    __shared__ float Ps[5 * PSPAN];   // 6.1 KB
    const int tid = threadIdx.x;
    const int slice = blockIdx.y, b = blockIdx.z;
    const int u0 = blockIdx.x * 256;
    const int f_base = slice < 4 ? slice * 5 : 20 + (slice - 4) * 4;
    const int nf     = slice < 4 ? 5 : 4;

    for (int i = tid; i < nf * PSPAN; i += 256) {
        int fl = i / PSPAN, j = i % PSPAN;
        const float* hr = h2 + (size_t)(b * F + f_base + fl) * T1;
        int s = u0 + j;
        int s0 = s     < T1 - 1 ? s     : T1 - 1;
        int s1 = s + 1 < T1 - 1 ? s + 1 : T1 - 1;
        int s2 = s + 2 < T1 - 1 ? s + 2 : T1 - 1;
        Ps[i] = (hr[s0] + hr[s1] + hr[s2]) * (1.f / 3.f);
    }
    __syncthreads();

    const int lu = tid;                        // wave = 64 consecutive u

    float acc[F];
    #pragma unroll
    for (int j = 0; j < F; ++j) acc[j] = 0.f;

    for (int fl = 0; fl < nf; ++fl) {
        const int pb = fl * PSPAN + lu;
        #pragma unroll 5
        for (int k = 0; k < KS; ++k) {
            float pv = Ps[pb + 3 * k];
            const float* wr = wcT + ((f_base + fl) * KS + k) * F;  // uniform
            #pragma unroll
            for (int j = 0; j < F; ++j) acc[j] += pv * wr[j];
        }
    }

    int u_g = u0 + lu;
    if (u_g < UN) {
        #pragma unroll
        for (int j = 0; j < F; ++j)
            Ep[(((size_t)slice * B + b) * F + j) * UN + u_g] = acc[j];
    }
}

// ---- K3: combine Ep + bn_c + elu, window sums, fused FC -> atomicAdd out ---
__global__ __launch_bounds__(256) void k_wins(
    const float* __restrict__ Ep, const float* __restrict__ bnz,
    const float* __restrict__ w_fc, float* __restrict__ out)
{
    __shared__ float Es[UN];
    __shared__ float G[GN];
    __shared__ float Ws[WN];
    __shared__ float Sm[M43];
    const int tid = threadIdx.x;
    const int bf = blockIdx.x;
    const int b = bf / F, f = bf % F;
    const float sc = bnz[4 * F + f];
    const float oc = bnz[5 * F + f];
    for (int i = tid; i < UN; i += 256) {
        float s = 0.f;
        #pragma unroll
        for (int sl = 0; sl < 8; ++sl)
            s += Ep[((size_t)sl * BF + bf) * UN + i];
        Es[i] = elu_f(s * sc + oc);
    }
    __syncthreads();
    for (int q = tid; q < GN; q += 256)
        G[q] = Es[3 * q] + Es[3 * q + 1] + Es[3 * q + 2];
    __syncthreads();
    if (tid < WN) {
        float a = 0.f;
        for (int q = tid; q < tid + 167; ++q) a += G[q];
        Ws[tid] = a;
    }
    __syncthreads();
    if (tid < M43)
        Sm[tid] = (Ws[3 * tid] + Ws[3 * tid + 1] + Ws[3 * tid + 2]) * (1.f / 3.f);
    __syncthreads();
    if (tid < 4) {
        const float* wr = w_fc + tid * FLAT + f * M43;
        float a = 0.f;
        #pragma unroll 43
        for (int m = 0; m < M43; ++m) a += Sm[m] * wr[m];
        atomicAdd(&out[b * 4 + tid], a * (1.f / 501.f));
    }
}

extern "C" void kernel_launch(void* const* d_in, const int* in_sizes, int n_in,
                              void* d_out, int out_size, void* d_ws, size_t ws_size,
                              hipStream_t stream) {
    const float* x    = (const float*)d_in[0];
    const float* w_t  = (const float*)d_in[1];
    const float* b_t  = (const float*)d_in[2];
    const float* g_t  = (const float*)d_in[3];
    const float* be_t = (const float*)d_in[4];
    const float* m_t  = (const float*)d_in[5];
    const float* v_t  = (const float*)d_in[6];
    const float* w_s  = (const float*)d_in[7];
    const float* b_s  = (const float*)d_in[8];
    const float* g_s  = (const float*)d_in[9];
    const float* be_s = (const float*)d_in[10];
    const float* m_s  = (const float*)d_in[11];
    const float* v_s  = (const float*)d_in[12];
    const float* w_c  = (const float*)d_in[13];
    const float* b_c  = (const float*)d_in[14];
    const float* g_c  = (const float*)d_in[15];
    const float* be_c = (const float*)d_in[16];
    const float* m_c  = (const float*)d_in[17];
    const float* v_c  = (const float*)d_in[18];
    const float* w_fc = (const float*)d_in[19];
    const float* b_fc = (const float*)d_in[20];

    float* ws  = (float*)d_ws;
    float* h2  = ws + H2_OFF;
    float* Ep  = ws + EP_OFF;
    float* wtT = ws + WTT_OFF;
    float* wsT = ws + WST_OFF;
    float* wcT = ws + WCT_OFF;
    float* bnz = ws + BN_OFF;
    float* h1  = ws + H1_OFF;
    float* out = (float*)d_out;

    // slab the t-dimension so h1 fits whatever scratch we actually have
    long long availF = (long long)(ws_size / 4) - (long long)H1_OFF;
    long long tsl = availF / (B * FC);
    int TS;
    if (tsl >= T1) TS = T1;
    else { TS = (int)(tsl & ~63LL); if (TS < 64) TS = 64; }
    int nslab = (T1 + TS - 1) / TS;

    k_prep<<<dim3(112), 256, 0, stream>>>(
        w_t, w_s, w_c, b_t, g_t, be_t, m_t, v_t,
        b_s, g_s, be_s, m_s, v_s, b_c, g_c, be_c, m_c, v_c, b_fc,
        wtT, wsT, wcT, bnz, out);

    for (int sl = 0; sl < nslab; ++sl) {
        int t_base = sl * TS;
        int TSeff = T1 - t_base; if (TSeff > TS) TSeff = TS;
        k_tconv<<<dim3((TSeff + 255) / 256, CH, B), 256, 0, stream>>>(
            x, wtT, bnz, h1, t_base, TS, TSeff);
        k_sconv<<<dim3((TSeff + 63) / 64, B), 512, 0, stream>>>(
            h1, wsT, bnz, h2, t_base, TS, TSeff);
    }

    k_qconv<<<dim3(4, 8, B), 256, 0, stream>>>(h2, wcT, Ep);
    k_wins<<<dim3(BF), 256, 0, stream>>>(Ep, bnz, w_fc, out);
}